// Round 2
// baseline (120.329 us; speedup 1.0000x reference)
//
#include <hip/hip_runtime.h>
#include <math.h>

#define BATCH 64
#define KSL   32
#define DIM   256
#define NMASK 16384

// ---------------------------------------------------------------------------
// Fused kernel:
//   blocks [0,64)        : per-batch cost matrix (in LDS) + reference-exact
//                          greedy assignment (the reference's "_hungarian"
//                          never writes minv/way back -> it is a greedy
//                          chain with dual potentials, NOT true Hungarian).
//   blocks [64, 64+2048) : mask partial sums (the 134 MB of traffic).
// ---------------------------------------------------------------------------
__global__ __launch_bounds__(256) void fused_kernel(
    const float* __restrict__ slots_t, const float* __restrict__ slots_t1,
    const float* __restrict__ masks,
    int* __restrict__ match, float* __restrict__ partial) {
  int tid = threadIdx.x;
  if (blockIdx.x < BATCH) {
    int b = blockIdx.x;
    __shared__ float as[KSL][64];
    __shared__ float bs[KSL][65];   // pad: bank (j*65+d)%32=(j+d)%32, conflict-free
    __shared__ float cs[KSL][KSL];
    const float* ab = slots_t  + (size_t)b * KSL * DIM;
    const float* bb = slots_t1 + (size_t)b * KSL * DIM;

    // ---- cost[i][j] = ||a_i - b_j||  (fp32, like the reference) ----
    float acc[4] = {0.f, 0.f, 0.f, 0.f};
    for (int c = 0; c < DIM / 64; ++c) {
      __syncthreads();
      for (int e = tid; e < KSL * 64; e += 256) {
        int kk = e >> 6, dd = e & 63;
        as[kk][dd] = ab[kk * DIM + c * 64 + dd];
        bs[kk][dd] = bb[kk * DIM + c * 64 + dd];
      }
      __syncthreads();
      #pragma unroll
      for (int p4 = 0; p4 < 4; ++p4) {
        int id = p4 * 256 + tid;
        int i = id >> 5, j = id & 31;
        float s = acc[p4];
        #pragma unroll
        for (int dd = 0; dd < 64; ++dd) {
          float df = as[i][dd] - bs[j][dd];
          s = fmaf(df, df, s);
        }
        acc[p4] = s;
      }
    }
    __syncthreads();
    #pragma unroll
    for (int p4 = 0; p4 < 4; ++p4) {
      int id = p4 * 256 + tid;
      cs[id >> 5][id & 31] = sqrtf(acc[p4]);
    }
    __syncthreads();
    if (tid >= 64) return;   // wave 0 solves alone; no barriers below

    // ---- reference-exact greedy (fp64 duals, fp32 cost upcast) ----
    // lane l (l&31 = col) holds: v[col+1], p[col+1], u[p[col+1]]
    // lanes 32..63 mirror lanes 0..31 (keeps all shuffles well-defined)
    const double INF = HUGE_VAL;
    int col = tid & 31;
    double v = 0.0, up = 0.0;
    int pcol = 0;
    for (int i = 1; i <= KSL; ++i) {
      double u_i = 0.0;     // u[i]: row i was never assigned before -> 0
      int used = 0;
      int j0 = 0;
      for (;;) {
        if (j0 > 0 && col == j0 - 1) used = 1;   // used[j0] = True
        int i0; double u0;
        if (j0 == 0) { i0 = i; u0 = u_i; }
        else {
          i0 = __shfl(pcol, j0 - 1);   // i0 = p[j0]
          u0 = __shfl(up,   j0 - 1);   // u[i0]
        }
        double cur = (double)cs[i0 - 1][col] - u0 - v;
        // masked = used ? INF : cur ; argmin, lowest index on tie (numpy)
        double mv = used ? INF : cur;
        int mj = col;
        #pragma unroll
        for (int off = 1; off < 32; off <<= 1) {
          double ov = __shfl_xor(mv, off);
          int    oj = __shfl_xor(mj, off);
          if (ov < mv || (ov == mv && oj < mj)) { mv = ov; mj = oj; }
        }
        double delta = mv;
        int j1 = mj + 1;
        // u[p[j]] += delta, v[j] -= delta for used j ; u[p[0]]=u[i] += delta
        if (used) { up += delta; v -= delta; }
        u_i += delta;
        j0 = j1;
        int pj = __shfl(pcol, j0 - 1);
        if (pj == 0) break;            // free column reached
      }
      // way[] is all-zero in the reference -> augment is just p[j0] = i
      if (col == j0 - 1) { pcol = i; up = u_i; }
    }
    if (tid < 32) match[b * KSL + (pcol - 1)] = col;  // ans[p[j]-1] = j-1
  } else {
    // ---- mask partial sums: partial[b][chunk][k], 134 MB coalesced ----
    int idx = blockIdx.x - BATCH;
    int b = idx >> 5, chunk = idx & 31;
    const int ROWS = NMASK / 32;  // 512 rows of 32 floats per chunk
    const float4* m4 = (const float4*)(masks + (size_t)b * NMASK * KSL +
                                       (size_t)chunk * ROWS * KSL);
    int q = tid & 7;        // float4 slot within row (8 per row)
    int r = tid >> 3;       // row group 0..31
    float4 acc4 = make_float4(0.f, 0.f, 0.f, 0.f);
    for (int rr = r; rr < ROWS; rr += 32) {
      float4 t = m4[rr * 8 + q];
      acc4.x += t.x; acc4.y += t.y; acc4.z += t.z; acc4.w += t.w;
    }
    __shared__ float red[256][4];
    red[tid][0] = acc4.x; red[tid][1] = acc4.y;
    red[tid][2] = acc4.z; red[tid][3] = acc4.w;
    __syncthreads();
    if (tid < KSL) {
      int qq = tid >> 2, c = tid & 3;
      float s = 0.f;
      for (int g = 0; g < 32; ++g) s += red[g * 8 + qq][c];
      partial[(size_t)b * 1024 + chunk * 32 + tid] = s;
    }
  }
}

// ---------------------------------------------------------------------------
// Epilogue: reduce util partials, matched L2^2 per slot, weight, per-batch sum
// ---------------------------------------------------------------------------
__global__ __launch_bounds__(256) void final_kernel(
    const float* __restrict__ st, const float* __restrict__ st1,
    const int* __restrict__ match, const float* __restrict__ partial,
    float* __restrict__ bloss) {
  int b = blockIdx.x, tid = threadIdx.x;
  __shared__ float util[KSL], ls[KSL], red[256];
  if (tid < KSL) {
    float s = 0.f;
    for (int c = 0; c < 32; ++c) s += partial[(size_t)b * 1024 + c * 32 + tid];
    util[tid] = s;
  }
  int k = tid >> 3, l8 = tid & 7;
  int mk = match[b * KSL + k];
  const float* x = st  + ((size_t)b * KSL + k)  * DIM;
  const float* y = st1 + ((size_t)b * KSL + mk) * DIM;
  float acc = 0.f;
  for (int d = l8; d < DIM; d += 8) {
    float df = x[d] - y[d];
    acc = fmaf(df, df, acc);
  }
  red[tid] = acc;
  __syncthreads();
  if (l8 == 0) {
    float s = 0.f;
    #pragma unroll
    for (int t = 0; t < 8; ++t) s += red[tid + t];
    ls[k] = s;
  }
  __syncthreads();
  if (tid == 0) {
    float us = 0.f;
    for (int kk = 0; kk < KSL; ++kk) us += util[kk];
    float s = 0.f;
    for (int kk = 0; kk < KSL; ++kk) s += ls[kk] * (util[kk] / us);
    bloss[b] = s;
  }
}

__global__ void reduce_kernel(const float* __restrict__ bloss,
                              float* __restrict__ out) {
  float v = bloss[threadIdx.x];
  #pragma unroll
  for (int off = 32; off > 0; off >>= 1) v += __shfl_down(v, off);
  if (threadIdx.x == 0) out[0] = v / (float)(BATCH * KSL);
}

extern "C" void kernel_launch(void* const* d_in, const int* in_sizes, int n_in,
                              void* d_out, int out_size, void* d_ws, size_t ws_size,
                              hipStream_t stream) {
  const float* slots_t  = (const float*)d_in[0];
  const float* slots_t1 = (const float*)d_in[1];
  const float* masks    = (const float*)d_in[2];

  // workspace layout: match 8KB | partial 256KB | bloss 256B
  char* ws = (char*)d_ws;
  int*   match   = (int*)  (ws);
  float* partial = (float*)(ws + 2048 * 4);
  float* bloss   = (float*)(ws + 2048 * 4 + 65536 * 4);

  fused_kernel<<<BATCH + BATCH * 32, 256, 0, stream>>>(slots_t, slots_t1, masks,
                                                       match, partial);
  final_kernel<<<BATCH, 256, 0, stream>>>(slots_t, slots_t1, match, partial, bloss);
  reduce_kernel<<<1, 64, 0, stream>>>(bloss, (float*)d_out);
}

// Round 3
// 63.859 us; speedup vs baseline: 1.8843x; 1.8843x over previous
//
#include <hip/hip_runtime.h>
#include <math.h>

#define BATCH 64
#define KSL   32
#define DIM   256
#define NMASK 16384

// DPP move of a double (both 32-bit halves), compile-time ctrl.
// bound_ctrl=false + old=src: invalid source lanes keep own value (min-safe).
template<int CTRL>
__device__ __forceinline__ double dpp_mov_f64(double x) {
  union { double d; int i[2]; } a, r;
  a.d = x;
  r.i[0] = __builtin_amdgcn_update_dpp(a.i[0], a.i[0], CTRL, 0xF, 0xF, false);
  r.i[1] = __builtin_amdgcn_update_dpp(a.i[1], a.i[1], CTRL, 0xF, 0xF, false);
  return r.d;
}

__device__ __forceinline__ double readlane_f64(double x, int lane) {
  union { double d; unsigned long long u; } a; a.d = x;
  int lo = __builtin_amdgcn_readlane((int)(a.u & 0xFFFFFFFFull), lane);
  int hi = __builtin_amdgcn_readlane((int)(a.u >> 32), lane);
  union { unsigned long long u; double d; } r;
  r.u = ((unsigned long long)(unsigned)hi << 32) | (unsigned)lo;
  return r.d;
}

// ---------------------------------------------------------------------------
// Fused kernel:
//   blocks [0,64)        : cost matrix in LDS + reference-exact greedy
//                          assignment (fp64 duals; reference's minv/way are
//                          never written back -> plain greedy chain).
//   blocks [64, 64+2048) : mask partial sums (the 134 MB of traffic).
// ---------------------------------------------------------------------------
__global__ __launch_bounds__(256) void fused_kernel(
    const float* __restrict__ slots_t, const float* __restrict__ slots_t1,
    const float* __restrict__ masks,
    int* __restrict__ match, float* __restrict__ partial) {
  int tid = threadIdx.x;
  if (blockIdx.x < BATCH) {
    int b = blockIdx.x;
    __shared__ float as[KSL][64];
    __shared__ float bs[KSL][65];   // pad: conflict-free
    __shared__ float cs[KSL][KSL];
    const float* ab = slots_t  + (size_t)b * KSL * DIM;
    const float* bb = slots_t1 + (size_t)b * KSL * DIM;

    // ---- cost[i][j] = ||a_i - b_j|| (fp32) ----
    float acc[4] = {0.f, 0.f, 0.f, 0.f};
    for (int c = 0; c < DIM / 64; ++c) {
      __syncthreads();
      for (int e = tid; e < KSL * 64; e += 256) {
        int kk = e >> 6, dd = e & 63;
        as[kk][dd] = ab[kk * DIM + c * 64 + dd];
        bs[kk][dd] = bb[kk * DIM + c * 64 + dd];
      }
      __syncthreads();
      #pragma unroll
      for (int p4 = 0; p4 < 4; ++p4) {
        int id = p4 * 256 + tid;
        int i = id >> 5, j = id & 31;
        float s = acc[p4];
        #pragma unroll
        for (int dd = 0; dd < 64; ++dd) {
          float df = as[i][dd] - bs[j][dd];
          s = fmaf(df, df, s);
        }
        acc[p4] = s;
      }
    }
    __syncthreads();
    #pragma unroll
    for (int p4 = 0; p4 < 4; ++p4) {
      int id = p4 * 256 + tid;
      cs[id >> 5][id & 31] = sqrtf(acc[p4]);
    }
    __syncthreads();
    if (tid >= 32) return;   // 32 lanes solve; no barriers below

    // ---- reference-exact greedy (fp64 duals, fp32 cost upcast) ----
    // lane col holds: v[col+1], p[col+1] (pcol), u[p[col+1]] (up)
    const int col = tid;
    double v = 0.0, up = 0.0;
    int pcol = 0;
    unsigned freemask = 0xFFFFFFFFu;   // uniform: bit j set <=> p[j+1]==0
    for (int i = 1; i <= KSL; ++i) {
      double u_i = 0.0;
      int used = 0;
      int i0 = i;          // p[0] = i
      double u0 = 0.0;     // u[i] = 0 (row i unassigned so far)
      for (;;) {
        double cur = (double)cs[i0 - 1][col] - u0 - v;
        double masked = used ? __builtin_inf() : cur;
        // 32-lane fp64 min via DPP: quad xor1, xor2, half-mirror, mirror,
        // bcast15 (lane 31 ends with min of all 32 lanes). Exact selection.
        double m = masked;
        m = fmin(m, dpp_mov_f64<0xB1>(m));    // quad_perm [1,0,3,2]
        m = fmin(m, dpp_mov_f64<0x4E>(m));    // quad_perm [2,3,0,1]
        m = fmin(m, dpp_mov_f64<0x141>(m));   // row_half_mirror
        m = fmin(m, dpp_mov_f64<0x140>(m));   // row_mirror
        m = fmin(m, dpp_mov_f64<0x142>(m));   // row_bcast15
        double delta = readlane_f64(m, 31);   // uniform min value
        // j1 = lowest col attaining the min (numpy argmin tie-break)
        unsigned eq = (unsigned)__ballot(masked == delta);
        int j1c = __builtin_amdgcn_readfirstlane(__ffs(eq) - 1);
        // prefetch next hop BEFORE dual update (lane j1c's up/pcol are
        // unchanged this iteration: j1c was unused during the update)
        double u0n = readlane_f64(up, j1c);
        int    i0n = __builtin_amdgcn_readlane(pcol, j1c);
        // dual updates: u[p[j]] += delta, v[j] -= delta for used j; u[i] too
        if (used) { up += delta; v -= delta; }
        u_i += delta;
        if (freemask & (1u << j1c)) {        // free column -> assign p[j1]=i
          if (col == j1c) { pcol = i; up = u_i; }
          freemask &= ~(1u << j1c);
          break;
        }
        if (col == j1c) used = 1;            // used[j1] = True
        u0 = u0n;
        i0 = i0n;
      }
    }
    match[b * KSL + (pcol - 1)] = col;       // ans[p[j]-1] = j-1
  } else {
    // ---- mask partial sums: partial[b][chunk][k], coalesced float4 ----
    int idx = blockIdx.x - BATCH;
    int b = idx >> 5, chunk = idx & 31;
    const int ROWS = NMASK / 32;  // 512 rows of 32 floats per chunk
    const float4* m4 = (const float4*)(masks + (size_t)b * NMASK * KSL +
                                       (size_t)chunk * ROWS * KSL);
    int q = tid & 7;
    int r = tid >> 3;
    float4 acc4 = make_float4(0.f, 0.f, 0.f, 0.f);
    for (int rr = r; rr < ROWS; rr += 32) {
      float4 t = m4[rr * 8 + q];
      acc4.x += t.x; acc4.y += t.y; acc4.z += t.z; acc4.w += t.w;
    }
    __shared__ float red[256][4];
    red[tid][0] = acc4.x; red[tid][1] = acc4.y;
    red[tid][2] = acc4.z; red[tid][3] = acc4.w;
    __syncthreads();
    if (tid < KSL) {
      int qq = tid >> 2, c = tid & 3;
      float s = 0.f;
      for (int g = 0; g < 32; ++g) s += red[g * 8 + qq][c];
      partial[(size_t)b * 1024 + chunk * 32 + tid] = s;
    }
  }
}

// ---------------------------------------------------------------------------
// Epilogue: reduce util partials, matched L2^2 per slot, weight, per-batch sum
// ---------------------------------------------------------------------------
__global__ __launch_bounds__(256) void final_kernel(
    const float* __restrict__ st, const float* __restrict__ st1,
    const int* __restrict__ match, const float* __restrict__ partial,
    float* __restrict__ bloss) {
  int b = blockIdx.x, tid = threadIdx.x;
  __shared__ float util[KSL], ls[KSL], red[256];
  if (tid < KSL) {
    float s = 0.f;
    for (int c = 0; c < 32; ++c) s += partial[(size_t)b * 1024 + c * 32 + tid];
    util[tid] = s;
  }
  int k = tid >> 3, l8 = tid & 7;
  int mk = match[b * KSL + k];
  const float* x = st  + ((size_t)b * KSL + k)  * DIM;
  const float* y = st1 + ((size_t)b * KSL + mk) * DIM;
  float acc = 0.f;
  for (int d = l8; d < DIM; d += 8) {
    float df = x[d] - y[d];
    acc = fmaf(df, df, acc);
  }
  red[tid] = acc;
  __syncthreads();
  if (l8 == 0) {
    float s = 0.f;
    #pragma unroll
    for (int t = 0; t < 8; ++t) s += red[tid + t];
    ls[k] = s;
  }
  __syncthreads();
  if (tid == 0) {
    float us = 0.f;
    for (int kk = 0; kk < KSL; ++kk) us += util[kk];
    float s = 0.f;
    for (int kk = 0; kk < KSL; ++kk) s += ls[kk] * (util[kk] / us);
    bloss[b] = s;
  }
}

__global__ void reduce_kernel(const float* __restrict__ bloss,
                              float* __restrict__ out) {
  float v = bloss[threadIdx.x];
  #pragma unroll
  for (int off = 32; off > 0; off >>= 1) v += __shfl_down(v, off);
  if (threadIdx.x == 0) out[0] = v / (float)(BATCH * KSL);
}

extern "C" void kernel_launch(void* const* d_in, const int* in_sizes, int n_in,
                              void* d_out, int out_size, void* d_ws, size_t ws_size,
                              hipStream_t stream) {
  const float* slots_t  = (const float*)d_in[0];
  const float* slots_t1 = (const float*)d_in[1];
  const float* masks    = (const float*)d_in[2];

  // workspace layout: match 8KB | partial 256KB | bloss 256B
  char* ws = (char*)d_ws;
  int*   match   = (int*)  (ws);
  float* partial = (float*)(ws + 2048 * 4);
  float* bloss   = (float*)(ws + 2048 * 4 + 65536 * 4);

  fused_kernel<<<BATCH + BATCH * 32, 256, 0, stream>>>(slots_t, slots_t1, masks,
                                                       match, partial);
  final_kernel<<<BATCH, 256, 0, stream>>>(slots_t, slots_t1, match, partial, bloss);
  reduce_kernel<<<1, 64, 0, stream>>>(bloss, (float*)d_out);
}